// Round 10
// baseline (146.784 us; speedup 1.0000x reference)
//
#include <hip/hip_runtime.h>
#include <stdint.h>

#define N 4096
#define D 1024            // elements per row; fp8 => 1024 bytes per row
#define MARGIN 0.1f
#define BM 128
#define BN 128
#define BKB 128           // K-slab per tile in fp8 bytes (=128 elements)
#define SCALE_ONE 0x7F    // e8m0 encoding of 1.0

typedef __attribute__((ext_vector_type(4))) float f32x4;
typedef __attribute__((ext_vector_type(8))) int i32x8;

// Kernel 1: one wave per row (4 rows/block): fp32 norms + diagonal dot,
// butterfly shfl_xor reduce, write normalized rows as OCP fp8 e4m3.
// Block 0 zeroes d_out. d_i stays fp32 (the only correlated error path).
__global__ __launch_bounds__(256) void prep_kernel(
    const float* __restrict__ W, const float* __restrict__ O,
    uint8_t* __restrict__ Wn, uint8_t* __restrict__ On,
    float* __restrict__ dvec, float* __restrict__ out) {
  const int wv = threadIdx.x >> 6, ln = threadIdx.x & 63;
  const int row = blockIdx.x * 4 + wv;
  if (blockIdx.x == 0 && threadIdx.x == 0) *out = 0.0f;
  const float4* Wr = (const float4*)(W + (size_t)row * D);
  const float4* Or = (const float4*)(O + (size_t)row * D);
  float4 w[4], o[4];
  float sw = 0.f, so = 0.f, sd = 0.f;
  #pragma unroll
  for (int c = 0; c < 4; ++c) {
    w[c] = Wr[ln + c * 64];
    o[c] = Or[ln + c * 64];
    sw += w[c].x * w[c].x + w[c].y * w[c].y + w[c].z * w[c].z + w[c].w * w[c].w;
    so += o[c].x * o[c].x + o[c].y * o[c].y + o[c].z * o[c].z + o[c].w * o[c].w;
    sd += w[c].x * o[c].x + w[c].y * o[c].y + w[c].z * o[c].z + w[c].w * o[c].w;
  }
  #pragma unroll
  for (int off = 1; off < 64; off <<= 1) {
    sw += __shfl_xor(sw, off, 64);
    so += __shfl_xor(so, off, 64);
    sd += __shfl_xor(sd, off, 64);
  }
  const float inw = 1.0f / sqrtf(sw);
  const float ino = 1.0f / sqrtf(so);
  if (ln == 0) dvec[row] = sd * inw * ino;
  int* Wo = (int*)(Wn + (size_t)row * D);
  int* Oo = (int*)(On + (size_t)row * D);
  #pragma unroll
  for (int c = 0; c < 4; ++c) {
    int pw = __builtin_amdgcn_cvt_pk_fp8_f32(w[c].x * inw, w[c].y * inw, 0, false);
    pw = __builtin_amdgcn_cvt_pk_fp8_f32(w[c].z * inw, w[c].w * inw, pw, true);
    int po = __builtin_amdgcn_cvt_pk_fp8_f32(o[c].x * ino, o[c].y * ino, 0, false);
    po = __builtin_amdgcn_cvt_pk_fp8_f32(o[c].z * ino, o[c].w * ino, po, true);
    Wo[ln + c * 64] = pw;
    Oo[ln + c * 64] = po;
  }
}

// Kernel 2: 128x128-tile MX-fp8 (K=128) MFMA GEMM + fused loss epilogue.
// R10 thesis: R6/R8 invariance (wall 55us at 1x and 1.5x DS, 1x and 2x
// occupancy) => 16x16x32-family was MFMA-pipe/issue-bound (16.6us/SIMD
// floor). mfma_scale_f32_16x16x128_f8f6f4 with scale=1.0 (e8m0 0x7F) is
// numerically identical to R9's fp8 GEMM but 4x fewer MFMA issues at ~2x
// rate (m148): MFMA floor 16.6 -> 7.4us; DS (~13us/CU) becomes the floor.
// A/B fragment: lane holds 32 CONTIGUOUS k-bytes at k0=(lane>>4)*32
// (natural extension of the octet layout R9 validated). Granule swizzle
// g^(r&7) retained: b128 frag reads land 2 lanes/slot = free (m136).
// NO min-occupancy launch_bounds (R5 lesson: unified VGPR/AGPR file).
__global__ __launch_bounds__(256) void gemm_loss_kernel(
    const uint8_t* __restrict__ Wn, const uint8_t* __restrict__ On,
    const float* __restrict__ dvec, float* __restrict__ out) {
  __shared__ __align__(16) uint8_t ldsA[BM * BKB];  // 16 KB
  __shared__ __align__(16) uint8_t ldsB[BN * BKB];  // 16 KB
  const int bx = blockIdx.x, by = blockIdx.y;
  const int t = threadIdx.x;
  const int wv = t >> 6, ln = t & 63;
  const int wm = wv >> 1, wn = wv & 1;   // 2x2 wave grid, 64x64 per wave
  const int lrow = ln & 15;
  const int quad = ln >> 4;
  const int l7 = lrow & 7;               // == rr&7 == cc&7 for fragment rows

  f32x4 acc[4][4] = {};

  const uint8_t* Ag = Wn + (size_t)(by * BM) * D;
  const uint8_t* Bg = On + (size_t)(bx * BN) * D;

  // swizzled byte offsets of this lane's two 16B granules within a row
  const int goff0 = (((2 * quad) ^ l7) << 4);
  const int goff1 = (((2 * quad + 1) ^ l7) << 4);

  for (int kt = 0; kt < D / BKB; ++kt) {           // 8 slabs
    // stage 128 rows x 128 B per tile = 1024 granules(16B); 256 thr x 4 rounds
    #pragma unroll
    for (int c = 0; c < 4; ++c) {
      const int g = c * 256 + t;         // granule index (fixed LDS slot)
      const int r = g >> 3;              // tile row (8 granules per row)
      const int gi = g & 7;              // granule slot within row
      const int col = (gi ^ (r & 7)) << 4;  // swizzled global byte col
      __builtin_amdgcn_global_load_lds(
          (const __attribute__((address_space(1))) void*)(Ag + (size_t)r * D + kt * BKB + col),
          (__attribute__((address_space(3))) void*)(ldsA + g * 16), 16, 0, 0);
      __builtin_amdgcn_global_load_lds(
          (const __attribute__((address_space(1))) void*)(Bg + (size_t)r * D + kt * BKB + col),
          (__attribute__((address_space(3))) void*)(ldsB + g * 16), 16, 0, 0);
    }
    __syncthreads();

#if __has_builtin(__builtin_amdgcn_mfma_scale_f32_16x16x128_f8f6f4)
    // One K=128 step per slab: 4 A-frags + 4 B-frags (32 B each = 2x b128),
    // 16 scaled MFMAs. scale=1.0 => bit-exact with the R9 fp8 path.
    i32x8 aF[4], bF[4];
    #pragma unroll
    for (int mi = 0; mi < 4; ++mi) {
      const uint8_t* base = ldsA + (wm * 64 + mi * 16 + lrow) * BKB;
      const int4 lo = *(const int4*)(base + goff0);
      const int4 hi = *(const int4*)(base + goff1);
      aF[mi] = (i32x8){lo.x, lo.y, lo.z, lo.w, hi.x, hi.y, hi.z, hi.w};
    }
    #pragma unroll
    for (int ni = 0; ni < 4; ++ni) {
      const uint8_t* base = ldsB + (wn * 64 + ni * 16 + lrow) * BKB;
      const int4 lo = *(const int4*)(base + goff0);
      const int4 hi = *(const int4*)(base + goff1);
      bF[ni] = (i32x8){lo.x, lo.y, lo.z, lo.w, hi.x, hi.y, hi.z, hi.w};
    }
    #pragma unroll
    for (int mi = 0; mi < 4; ++mi)
      #pragma unroll
      for (int ni = 0; ni < 4; ++ni)
        acc[mi][ni] = __builtin_amdgcn_mfma_scale_f32_16x16x128_f8f6f4(
            aF[mi], bF[ni], acc[mi][ni], 0, 0,          // cbsz=fp8, blgp=fp8
            0, SCALE_ONE, 0, SCALE_ONE);                // opsel/scale A, B
#else
    // Fallback: R9's proven non-scaled fp8 path (4 k-steps of 32).
    #pragma unroll
    for (int kk = 0; kk < 4; ++kk) {
      const int gh = kk * 2 + (quad >> 1);
      const int sub = (quad & 1) * 8;
      long aF[4], bF[4];
      #pragma unroll
      for (int mi = 0; mi < 4; ++mi)
        aF[mi] = *(const long*)(ldsA + (wm * 64 + mi * 16 + lrow) * BKB +
                                ((gh ^ l7) << 4) + sub);
      #pragma unroll
      for (int ni = 0; ni < 4; ++ni)
        bF[ni] = *(const long*)(ldsB + (wn * 64 + ni * 16 + lrow) * BKB +
                                ((gh ^ l7) << 4) + sub);
      #pragma unroll
      for (int mi = 0; mi < 4; ++mi)
        #pragma unroll
        for (int ni = 0; ni < 4; ++ni)
          acc[mi][ni] = __builtin_amdgcn_mfma_f32_16x16x32_fp8_fp8(
              aF[mi], bF[ni], acc[mi][ni], 0, 0, 0);
    }
#endif
    __syncthreads();
  }

  // Epilogue: C/D layout col=lane&15, row=quad*4+reg (shape-determined,
  // dtype/FMT-independent — m89/m121/m127; R9 absmax=0 re-confirmed)
  float lsum = 0.0f;
  #pragma unroll
  for (int mi = 0; mi < 4; ++mi) {
    const int gibase = by * BM + wm * 64 + mi * 16 + quad * 4;
    #pragma unroll
    for (int r = 0; r < 4; ++r) {
      const int gi = gibase + r;
      const float di = dvec[gi];  // fp32 diagonal (accurate)
      #pragma unroll
      for (int ni = 0; ni < 4; ++ni) {
        const int gj = bx * BN + wn * 64 + ni * 16 + lrow;
        const float s = acc[mi][ni][r];
        lsum += (gi == gj) ? (1.0f - s) : fmaxf(MARGIN - s + di, 0.0f);
      }
    }
  }
  #pragma unroll
  for (int off = 32; off; off >>= 1) lsum += __shfl_down(lsum, off, 64);
  __shared__ float bsum[4];
  if (ln == 0) bsum[wv] = lsum;
  __syncthreads();
  if (t == 0) {
    const float tot = (bsum[0] + bsum[1] + bsum[2] + bsum[3]) *
                      (1.0f / ((float)N * (float)N));
    atomicAdd(out, tot);
  }
}

extern "C" void kernel_launch(void* const* d_in, const int* in_sizes, int n_in,
                              void* d_out, int out_size, void* d_ws, size_t ws_size,
                              hipStream_t stream) {
  const float* W = (const float*)d_in[0];  // wsi_embeddings (N,1,D)
  const float* O = (const float*)d_in[1];  // omic_embeddings (N,1,D)
  uint8_t* Wn = (uint8_t*)d_ws;                     // 4 MB fp8
  uint8_t* On = Wn + (size_t)N * D;                 // 4 MB fp8
  float* dvec = (float*)(On + (size_t)N * D);       // 16 KB
  float* out = (float*)d_out;

  prep_kernel<<<N / 4, 256, 0, stream>>>(W, O, Wn, On, dvec, out);
  dim3 grid(N / BN, N / BM);  // 32 x 32 = 1024 blocks
  gemm_loss_kernel<<<grid, 256, 0, stream>>>(Wn, On, dvec, out);
}

// Round 11
// 137.771 us; speedup vs baseline: 1.0654x; 1.0654x over previous
//
#include <hip/hip_runtime.h>
#include <stdint.h>

#define N 4096
#define D 1024            // elements per row; fp8 => 1024 bytes per row
#define MARGIN 0.1f
#define BM 64
#define BN 128
#define BKB 128           // K-slab per tile in fp8 bytes (=128 elements)
#define SCALE_ONE 0x7F    // e8m0 encoding of 1.0

typedef __attribute__((ext_vector_type(4))) float f32x4;
typedef __attribute__((ext_vector_type(8))) int i32x8;

// Kernel 1: one wave per row (4 rows/block): fp32 norms + diagonal dot,
// butterfly shfl_xor reduce, write normalized rows as OCP fp8 e4m3.
// Block 0 zeroes d_out. d_i stays fp32 (the only correlated error path).
__global__ __launch_bounds__(256) void prep_kernel(
    const float* __restrict__ W, const float* __restrict__ O,
    uint8_t* __restrict__ Wn, uint8_t* __restrict__ On,
    float* __restrict__ dvec, float* __restrict__ out) {
  const int wv = threadIdx.x >> 6, ln = threadIdx.x & 63;
  const int row = blockIdx.x * 4 + wv;
  if (blockIdx.x == 0 && threadIdx.x == 0) *out = 0.0f;
  const float4* Wr = (const float4*)(W + (size_t)row * D);
  const float4* Or = (const float4*)(O + (size_t)row * D);
  float4 w[4], o[4];
  float sw = 0.f, so = 0.f, sd = 0.f;
  #pragma unroll
  for (int c = 0; c < 4; ++c) {
    w[c] = Wr[ln + c * 64];
    o[c] = Or[ln + c * 64];
    sw += w[c].x * w[c].x + w[c].y * w[c].y + w[c].z * w[c].z + w[c].w * w[c].w;
    so += o[c].x * o[c].x + o[c].y * o[c].y + o[c].z * o[c].z + o[c].w * o[c].w;
    sd += w[c].x * o[c].x + w[c].y * o[c].y + w[c].z * o[c].z + w[c].w * o[c].w;
  }
  #pragma unroll
  for (int off = 1; off < 64; off <<= 1) {
    sw += __shfl_xor(sw, off, 64);
    so += __shfl_xor(so, off, 64);
    sd += __shfl_xor(sd, off, 64);
  }
  const float inw = 1.0f / sqrtf(sw);
  const float ino = 1.0f / sqrtf(so);
  if (ln == 0) dvec[row] = sd * inw * ino;
  int* Wo = (int*)(Wn + (size_t)row * D);
  int* Oo = (int*)(On + (size_t)row * D);
  #pragma unroll
  for (int c = 0; c < 4; ++c) {
    int pw = __builtin_amdgcn_cvt_pk_fp8_f32(w[c].x * inw, w[c].y * inw, 0, false);
    pw = __builtin_amdgcn_cvt_pk_fp8_f32(w[c].z * inw, w[c].w * inw, pw, true);
    int po = __builtin_amdgcn_cvt_pk_fp8_f32(o[c].x * ino, o[c].y * ino, 0, false);
    po = __builtin_amdgcn_cvt_pk_fp8_f32(o[c].z * ino, o[c].w * ino, po, true);
    Wo[ln + c * 64] = pw;
    Oo[ln + c * 64] = po;
  }
}

// Kernel 2: 64x128-tile MX-fp8 (K=128) MFMA GEMM + fused loss epilogue.
// R10: scaled path CORRECT (absmax 0.0) but 64x64 wave tile spilled
// (VGPR 256, WRITE_SIZE 86 MB, GEMM 83us). R11 fix: 32x64 wave tile —
// acc[2][4]=32 AGPR + aF[2]=16 + bF[4]=32 VGPR fits the unified file.
// R8 proved the 64x128 block shape is perf-neutral, so the only delta
// vs R10 is spill removal; MFMA-pipe floor 7.4us/SIMD (vs 16.6 fp8@K32).
// Granule swizzle g^(r&7) retained (2 lanes/slot = free). NO
// min-occupancy launch_bounds (R5 lesson).
__global__ __launch_bounds__(256) void gemm_loss_kernel(
    const uint8_t* __restrict__ Wn, const uint8_t* __restrict__ On,
    const float* __restrict__ dvec, float* __restrict__ out) {
  __shared__ __align__(16) uint8_t ldsA[BM * BKB];  // 8 KB
  __shared__ __align__(16) uint8_t ldsB[BN * BKB];  // 16 KB
  const int bx = blockIdx.x, by = blockIdx.y;
  const int t = threadIdx.x;
  const int wv = t >> 6, ln = t & 63;
  const int wm = wv >> 1, wn = wv & 1;   // 2x2 wave grid; wave = 32x64 of C
  const int lrow = ln & 15;
  const int quad = ln >> 4;
  const int l7 = lrow & 7;               // == rr&7 == cc&7 for fragment rows

  f32x4 acc[2][4] = {};

  const uint8_t* Ag = Wn + (size_t)(by * BM) * D;
  const uint8_t* Bg = On + (size_t)(bx * BN) * D;

  // swizzled byte offsets of this lane's two 16B granules within a row
  const int goff0 = (((2 * quad) ^ l7) << 4);
  const int goff1 = (((2 * quad + 1) ^ l7) << 4);

  for (int kt = 0; kt < D / BKB; ++kt) {           // 8 slabs
    // A-tile: 64 rows x 128 B = 512 granules(16B) = 2 rounds of 256 threads
    #pragma unroll
    for (int c = 0; c < 2; ++c) {
      const int g = c * 256 + t;
      const int r = g >> 3;
      const int gi = g & 7;
      const int col = (gi ^ (r & 7)) << 4;
      __builtin_amdgcn_global_load_lds(
          (const __attribute__((address_space(1))) void*)(Ag + (size_t)r * D + kt * BKB + col),
          (__attribute__((address_space(3))) void*)(ldsA + g * 16), 16, 0, 0);
    }
    // B-tile: 128 rows x 128 B = 1024 granules = 4 rounds
    #pragma unroll
    for (int c = 0; c < 4; ++c) {
      const int g = c * 256 + t;
      const int r = g >> 3;
      const int gi = g & 7;
      const int col = (gi ^ (r & 7)) << 4;
      __builtin_amdgcn_global_load_lds(
          (const __attribute__((address_space(1))) void*)(Bg + (size_t)r * D + kt * BKB + col),
          (__attribute__((address_space(3))) void*)(ldsB + g * 16), 16, 0, 0);
    }
    __syncthreads();

    // One K=128 step per slab: 2 A-frags + 4 B-frags (32 B each = 2x b128),
    // 8 scaled MFMAs. scale=1.0 (e8m0 0x7F) => bit-exact with R9 fp8 math.
    i32x8 aF[2], bF[4];
    #pragma unroll
    for (int mi = 0; mi < 2; ++mi) {
      const uint8_t* base = ldsA + (wm * 32 + mi * 16 + lrow) * BKB;
      const int4 lo = *(const int4*)(base + goff0);
      const int4 hi = *(const int4*)(base + goff1);
      aF[mi] = (i32x8){lo.x, lo.y, lo.z, lo.w, hi.x, hi.y, hi.z, hi.w};
    }
    #pragma unroll
    for (int ni = 0; ni < 4; ++ni) {
      const uint8_t* base = ldsB + (wn * 64 + ni * 16 + lrow) * BKB;
      const int4 lo = *(const int4*)(base + goff0);
      const int4 hi = *(const int4*)(base + goff1);
      bF[ni] = (i32x8){lo.x, lo.y, lo.z, lo.w, hi.x, hi.y, hi.z, hi.w};
    }
    #pragma unroll
    for (int mi = 0; mi < 2; ++mi)
      #pragma unroll
      for (int ni = 0; ni < 4; ++ni)
        acc[mi][ni] = __builtin_amdgcn_mfma_scale_f32_16x16x128_f8f6f4(
            aF[mi], bF[ni], acc[mi][ni], 0, 0,          // cbsz=fp8, blgp=fp8
            0, SCALE_ONE, 0, SCALE_ONE);                // opsel/scale A, B
    __syncthreads();
  }

  // Epilogue: C/D layout col=lane&15, row=quad*4+reg (shape-determined,
  // dtype/FMT-independent — m89/m121/m127; R10 absmax=0 confirmed for
  // the scaled instruction specifically)
  float lsum = 0.0f;
  #pragma unroll
  for (int mi = 0; mi < 2; ++mi) {
    const int gibase = by * BM + wm * 32 + mi * 16 + quad * 4;
    #pragma unroll
    for (int r = 0; r < 4; ++r) {
      const int gi = gibase + r;
      const float di = dvec[gi];  // fp32 diagonal (accurate)
      #pragma unroll
      for (int ni = 0; ni < 4; ++ni) {
        const int gj = bx * BN + wn * 64 + ni * 16 + lrow;
        const float s = acc[mi][ni][r];
        lsum += (gi == gj) ? (1.0f - s) : fmaxf(MARGIN - s + di, 0.0f);
      }
    }
  }
  #pragma unroll
  for (int off = 32; off; off >>= 1) lsum += __shfl_down(lsum, off, 64);
  __shared__ float bsum[4];
  if (ln == 0) bsum[wv] = lsum;
  __syncthreads();
  if (t == 0) {
    const float tot = (bsum[0] + bsum[1] + bsum[2] + bsum[3]) *
                      (1.0f / ((float)N * (float)N));
    atomicAdd(out, tot);
  }
}

extern "C" void kernel_launch(void* const* d_in, const int* in_sizes, int n_in,
                              void* d_out, int out_size, void* d_ws, size_t ws_size,
                              hipStream_t stream) {
  const float* W = (const float*)d_in[0];  // wsi_embeddings (N,1,D)
  const float* O = (const float*)d_in[1];  // omic_embeddings (N,1,D)
  uint8_t* Wn = (uint8_t*)d_ws;                     // 4 MB fp8
  uint8_t* On = Wn + (size_t)N * D;                 // 4 MB fp8
  float* dvec = (float*)(On + (size_t)N * D);       // 16 KB
  float* out = (float*)d_out;

  prep_kernel<<<N / 4, 256, 0, stream>>>(W, O, Wn, On, dvec, out);
  dim3 grid(N / BN, N / BM);  // (32, 64) = 2048 blocks
  gemm_loss_kernel<<<grid, 256, 0, stream>>>(Wn, On, dvec, out);
}

// Round 12
// 112.501 us; speedup vs baseline: 1.3047x; 1.2246x over previous
//
#include <hip/hip_runtime.h>
#include <stdint.h>

#define N 4096
#define D 1024            // elements per row; fp8 => 1024 bytes per row
#define MARGIN 0.1f
#define BM 64
#define BN 128
#define BKB 128           // K-slab per tile in fp8 bytes (=128 elements)
#define SCALE_ONE 0x7F    // e8m0 encoding of 1.0

typedef __attribute__((ext_vector_type(4))) float f32x4;
typedef __attribute__((ext_vector_type(8))) int i32x8;

// Kernel 1: one wave per row (4 rows/block): fp32 norms + diagonal dot,
// butterfly shfl_xor reduce, write normalized rows as OCP fp8 e4m3.
// Block 0 zeroes d_out. d_i stays fp32 (the only correlated error path).
__global__ __launch_bounds__(256) void prep_kernel(
    const float* __restrict__ W, const float* __restrict__ O,
    uint8_t* __restrict__ Wn, uint8_t* __restrict__ On,
    float* __restrict__ dvec, float* __restrict__ out) {
  const int wv = threadIdx.x >> 6, ln = threadIdx.x & 63;
  const int row = blockIdx.x * 4 + wv;
  if (blockIdx.x == 0 && threadIdx.x == 0) *out = 0.0f;
  const float4* Wr = (const float4*)(W + (size_t)row * D);
  const float4* Or = (const float4*)(O + (size_t)row * D);
  float4 w[4], o[4];
  float sw = 0.f, so = 0.f, sd = 0.f;
  #pragma unroll
  for (int c = 0; c < 4; ++c) {
    w[c] = Wr[ln + c * 64];
    o[c] = Or[ln + c * 64];
    sw += w[c].x * w[c].x + w[c].y * w[c].y + w[c].z * w[c].z + w[c].w * w[c].w;
    so += o[c].x * o[c].x + o[c].y * o[c].y + o[c].z * o[c].z + o[c].w * o[c].w;
    sd += w[c].x * o[c].x + w[c].y * o[c].y + w[c].z * o[c].z + w[c].w * o[c].w;
  }
  #pragma unroll
  for (int off = 1; off < 64; off <<= 1) {
    sw += __shfl_xor(sw, off, 64);
    so += __shfl_xor(so, off, 64);
    sd += __shfl_xor(sd, off, 64);
  }
  const float inw = 1.0f / sqrtf(sw);
  const float ino = 1.0f / sqrtf(so);
  if (ln == 0) dvec[row] = sd * inw * ino;
  int* Wo = (int*)(Wn + (size_t)row * D);
  int* Oo = (int*)(On + (size_t)row * D);
  #pragma unroll
  for (int c = 0; c < 4; ++c) {
    int pw = __builtin_amdgcn_cvt_pk_fp8_f32(w[c].x * inw, w[c].y * inw, 0, false);
    pw = __builtin_amdgcn_cvt_pk_fp8_f32(w[c].z * inw, w[c].w * inw, pw, true);
    int po = __builtin_amdgcn_cvt_pk_fp8_f32(o[c].x * ino, o[c].y * ino, 0, false);
    po = __builtin_amdgcn_cvt_pk_fp8_f32(o[c].z * ino, o[c].w * ino, po, true);
    Wo[ln + c * 64] = pw;
    Oo[ln + c * 64] = po;
  }
}

// Kernel 2: 64x128-tile MX-fp8 (K=128) MFMA GEMM + fused loss epilogue.
// R11: spill fixed but VGPR=220 -> 2 blocks/CU, latency-bound (67us).
// The 140 extra regs were the fully-unrolled kt loop's 48 precomputed
// staging addresses. R12: (1) #pragma unroll 1 on the kt loop — barriers
// forbid cross-slab overlap anyway, so unrolling only burns registers;
// (2) stream bF one fragment at a time (peak frag liveness 16+8+32).
// Target: ~130 VGPR -> 3 waves/SIMD -> 3 blocks/CU (R9's proven regime).
// Scaled-MFMA fragment layout + e8m0 scale=0x7F verified on HW (R10/R11
// absmax=0.0). Granule swizzle g^(r&7). NO min-occupancy bounds (R5).
__global__ __launch_bounds__(256) void gemm_loss_kernel(
    const uint8_t* __restrict__ Wn, const uint8_t* __restrict__ On,
    const float* __restrict__ dvec, float* __restrict__ out) {
  __shared__ __align__(16) uint8_t ldsA[BM * BKB];  // 8 KB
  __shared__ __align__(16) uint8_t ldsB[BN * BKB];  // 16 KB
  const int bx = blockIdx.x, by = blockIdx.y;
  const int t = threadIdx.x;
  const int wv = t >> 6, ln = t & 63;
  const int wm = wv >> 1, wn = wv & 1;   // 2x2 wave grid; wave = 32x64 of C
  const int lrow = ln & 15;
  const int quad = ln >> 4;
  const int l7 = lrow & 7;               // == rr&7 == cc&7 for fragment rows

  f32x4 acc[2][4] = {};

  // Staging base addresses for THIS thread (strength-reduced per slab).
  const int gA = t;                       // A granule round base (2 rounds)
  const int rA0 = gA >> 3, giA0 = gA & 7;
  const int rA1 = (gA + 256) >> 3, giA1 = (gA + 256) & 7;
  const uint8_t* Ag = Wn + (size_t)(by * BM) * D;
  const uint8_t* Bg = On + (size_t)(bx * BN) * D;

  // swizzled byte offsets of this lane's two 16B granules within a row
  const int goff0 = (((2 * quad) ^ l7) << 4);
  const int goff1 = (((2 * quad + 1) ^ l7) << 4);
  const uint8_t* aBase0 = ldsA + (wm * 32 + lrow) * BKB;          // mi=0
  const uint8_t* aBase1 = aBase0 + 16 * BKB;                      // mi=1
  const uint8_t* bBase = ldsB + (wn * 64 + lrow) * BKB;

  #pragma unroll 1
  for (int kt = 0; kt < D / BKB; ++kt) {           // 8 slabs, NOT unrolled
    const size_t kb = (size_t)kt * BKB;
    // A-tile: 64 rows x 128 B = 512 granules(16B) = 2 rounds of 256 threads
    __builtin_amdgcn_global_load_lds(
        (const __attribute__((address_space(1))) void*)(Ag + (size_t)rA0 * D + kb + ((giA0 ^ (rA0 & 7)) << 4)),
        (__attribute__((address_space(3))) void*)(ldsA + gA * 16), 16, 0, 0);
    __builtin_amdgcn_global_load_lds(
        (const __attribute__((address_space(1))) void*)(Ag + (size_t)rA1 * D + kb + ((giA1 ^ (rA1 & 7)) << 4)),
        (__attribute__((address_space(3))) void*)(ldsA + (gA + 256) * 16), 16, 0, 0);
    // B-tile: 128 rows x 128 B = 1024 granules = 4 rounds
    #pragma unroll
    for (int c = 0; c < 4; ++c) {
      const int g = c * 256 + t;
      const int r = g >> 3;
      const int gi = g & 7;
      __builtin_amdgcn_global_load_lds(
          (const __attribute__((address_space(1))) void*)(Bg + (size_t)r * D + kb + ((gi ^ (r & 7)) << 4)),
          (__attribute__((address_space(3))) void*)(ldsB + g * 16), 16, 0, 0);
    }
    __syncthreads();

    // One K=128 step per slab: aF[2] resident, bF streamed (8 scaled MFMAs).
    i32x8 aF[2];
    {
      const int4 lo0 = *(const int4*)(aBase0 + goff0);
      const int4 hi0 = *(const int4*)(aBase0 + goff1);
      aF[0] = (i32x8){lo0.x, lo0.y, lo0.z, lo0.w, hi0.x, hi0.y, hi0.z, hi0.w};
      const int4 lo1 = *(const int4*)(aBase1 + goff0);
      const int4 hi1 = *(const int4*)(aBase1 + goff1);
      aF[1] = (i32x8){lo1.x, lo1.y, lo1.z, lo1.w, hi1.x, hi1.y, hi1.z, hi1.w};
    }
    #pragma unroll
    for (int ni = 0; ni < 4; ++ni) {
      const uint8_t* base = bBase + ni * 16 * BKB;
      const int4 lo = *(const int4*)(base + goff0);
      const int4 hi = *(const int4*)(base + goff1);
      const i32x8 bF = (i32x8){lo.x, lo.y, lo.z, lo.w, hi.x, hi.y, hi.z, hi.w};
      acc[0][ni] = __builtin_amdgcn_mfma_scale_f32_16x16x128_f8f6f4(
          aF[0], bF, acc[0][ni], 0, 0, 0, SCALE_ONE, 0, SCALE_ONE);
      acc[1][ni] = __builtin_amdgcn_mfma_scale_f32_16x16x128_f8f6f4(
          aF[1], bF, acc[1][ni], 0, 0, 0, SCALE_ONE, 0, SCALE_ONE);
    }
    __syncthreads();
  }

  // Epilogue: C/D layout col=lane&15, row=quad*4+reg (shape-determined,
  // dtype/FMT-independent — m89/m121/m127; R10/R11 absmax=0 confirmed)
  float lsum = 0.0f;
  #pragma unroll
  for (int mi = 0; mi < 2; ++mi) {
    const int gibase = by * BM + wm * 32 + mi * 16 + quad * 4;
    #pragma unroll
    for (int r = 0; r < 4; ++r) {
      const int gi = gibase + r;
      const float di = dvec[gi];  // fp32 diagonal (accurate)
      #pragma unroll
      for (int ni = 0; ni < 4; ++ni) {
        const int gj = bx * BN + wn * 64 + ni * 16 + lrow;
        const float s = acc[mi][ni][r];
        lsum += (gi == gj) ? (1.0f - s) : fmaxf(MARGIN - s + di, 0.0f);
      }
    }
  }
  #pragma unroll
  for (int off = 32; off; off >>= 1) lsum += __shfl_down(lsum, off, 64);
  __shared__ float bsum[4];
  if (ln == 0) bsum[wv] = lsum;
  __syncthreads();
  if (t == 0) {
    const float tot = (bsum[0] + bsum[1] + bsum[2] + bsum[3]) *
                      (1.0f / ((float)N * (float)N));
    atomicAdd(out, tot);
  }
}

extern "C" void kernel_launch(void* const* d_in, const int* in_sizes, int n_in,
                              void* d_out, int out_size, void* d_ws, size_t ws_size,
                              hipStream_t stream) {
  const float* W = (const float*)d_in[0];  // wsi_embeddings (N,1,D)
  const float* O = (const float*)d_in[1];  // omic_embeddings (N,1,D)
  uint8_t* Wn = (uint8_t*)d_ws;                     // 4 MB fp8
  uint8_t* On = Wn + (size_t)N * D;                 // 4 MB fp8
  float* dvec = (float*)(On + (size_t)N * D);       // 16 KB
  float* out = (float*)d_out;

  prep_kernel<<<N / 4, 256, 0, stream>>>(W, O, Wn, On, dvec, out);
  dim3 grid(N / BN, N / BM);  // (32, 64) = 2048 blocks
  gemm_loss_kernel<<<grid, 256, 0, stream>>>(Wn, On, dvec, out);
}